// Round 6
// baseline (113.974 us; speedup 1.0000x reference)
//
#include <hip/hip_runtime.h>
#include <math.h>
#include <float.h>

#define EPS 1e-6f
#define THRESHOLD 0.5f

#define NB 16
#define NPOLY 16
#define NVERT 200
#define NSEG_PER_POLY 199
#define NSEG (NPOLY * NSEG_PER_POLY)   // 3184 segments per batch
#define NPTB 300                       // points per batch (10 agents * 30)
#define NPOINTS 4800                   // 16 * 300
#define NSLICE 64
#define SEG_PER_SLICE 50               // slices 0..62: 50 segs, slice 63: 34

// ---------------------------------------------------------------------------
// Single fused kernel: one block per (batch, segment-slice).
//  Prologue : threads 0..nseg-1 precompute their segment into LDS.
//  Main loop: lane = point; wave-uniform ds_read_b128 broadcasts; crossing
//             test = rcp fast path; exact-div fallback guarded by a
//             WAVE-UNIFORM __ballot branch (s_cbranch, no per-lane exec
//             surgery) — parity decision always bit-matches numpy ref.
//  Epilogue : rocPRIM-style last-block-per-batch finalize. Blocks store
//             float2{min_dsq, crossings} partials; acq_rel agent-scope
//             arrival counter per batch; the 64th block reduces all 64
//             partials for its batch and writes out[b*10..b*10+9] directly
//             (no atomics on out, no separate final kernel, poison covered).
// Exactness: slope_eps = (ey-sy)/((ex-sx)+EPS)+EPS (ref rounding order);
//            inv_esq feeds distance only; cond_y XOR-form is exact.
// ---------------------------------------------------------------------------
__global__ __launch_bounds__(320) void seg_kernel(
    const float* __restrict__ points,
    const float* __restrict__ polys,
    float2* __restrict__ part,        // [NSLICE][NPOINTS]
    int* __restrict__ ctr,            // [NB], zeroed before launch
    float* __restrict__ out)
{
    __shared__ float4 lds[SEG_PER_SLICE * 2];
    __shared__ float agent_sum[10];
    __shared__ int is_last;

    const int slice = blockIdx.x;       // 0..63
    const int b     = blockIdx.y;       // 0..15
    const int lp    = threadIdx.x;      // 0..319; points 0..299 valid
    const bool active = lp < NPTB;

    const int s0 = slice * SEG_PER_SLICE;
    const int s1 = (s0 + SEG_PER_SLICE < NSEG) ? s0 + SEG_PER_SLICE : NSEG;
    const int nseg = s1 - s0;

    // ---- prologue: per-segment precompute into LDS ----
    if (lp < nseg) {
        const int s = s0 + lp;
        const int m = s / NSEG_PER_POLY;
        const int v = s % NSEG_PER_POLY;
        const float2* poly = (const float2*)polys + ((size_t)(b * NPOLY + m) * NVERT);
        const float2 S = poly[v];
        const float2 E = poly[v + 1];
        const float evx = E.x - S.x;
        const float evy = E.y - S.y;
        const float esq = evx * evx + evy * evy;
        const float inv_esq = 1.0f / (esq + EPS);
        const float slope_eps = evy / (evx + EPS) + EPS;  // exact IEEE, ref order
        const float inv_slope = __builtin_amdgcn_rcpf(slope_eps);
        lds[lp * 2]     = make_float4(S.x, S.y, evx, evy);
        lds[lp * 2 + 1] = make_float4(inv_esq, slope_eps, inv_slope, E.y);
    }
    __syncthreads();

    const int pidx = b * NPTB + (active ? lp : 0);
    const float2 pt = *(const float2*)(points + (size_t)pidx * 2);
    const float px = pt.x, py = pt.y;

    float min_dsq = FLT_MAX;
    int crossings = 0;

    #pragma unroll 2
    for (int j = 0; j < nseg; ++j) {
        const float4 p0 = lds[j * 2];       // wave-uniform -> broadcast
        const float4 p1 = lds[j * 2 + 1];
        const float sx = p0.x, sy = p0.y, evx = p0.z, evy = p0.w;
        const float inv_esq = p1.x, slope_eps = p1.y, inv_slope = p1.z, ey = p1.w;

        // ---- point-to-segment squared distance (ulp-tolerant path) ----
        const float v1x = px - sx;
        const float v1y = py - sy;
        const float dot = v1x * evx + v1y * evy;
        float t = dot * inv_esq;
        t = fminf(fmaxf(t, 0.0f), 1.0f);
        const float dx = px - (evx * t + sx);
        const float dy = py - (evy * t + sy);
        const float dsq = dx * dx + dy * dy;
        min_dsq = fminf(min_dsq, dsq);

        // ---- even-odd crossing: rcp fast path, wave-uniform exact fallback ----
        const bool cond_y = (sy <= py) != (ey <= py);   // == ref's cond_y, exact
        const float q    = v1y * inv_slope;             // ~3 ulp
        const float ixa  = sx + q;
        const float diff = ixa - px;
        const float err  = fmaf(fabsf(q) + fabsf(ixa), 1e-6f, 1e-30f);
        bool left = diff > 0.0f;
        const bool uncertain = cond_y && !(fabsf(diff) > err);
        if (__ballot(uncertain)) {          // SGPR branch; ~never taken
            const float ix_exact = sx + v1y / slope_eps;  // bit-exact vs ref
            if (uncertain) left = ix_exact > px;
        }
        crossings += (cond_y && left) ? 1 : 0;
    }

    if (active) {
        part[slice * NPOINTS + pidx] = make_float2(min_dsq, __int_as_float(crossings));
    }
    __syncthreads();                 // all block stores complete (vmcnt drained)

    // ---- arrival: last block per batch finalizes ----
    if (threadIdx.x == 0) {
        __threadfence();             // push block's stores to device scope (wbL2)
        const int old = __hip_atomic_fetch_add(&ctr[b], 1, __ATOMIC_ACQ_REL,
                                               __HIP_MEMORY_SCOPE_AGENT);
        is_last = (old == NSLICE - 1) ? 1 : 0;
        if (is_last) __threadfence();  // acquire: invalidate stale cache lines
    }
    __syncthreads();
    if (!is_last) return;

    if (lp < 10) agent_sum[lp] = 0.0f;
    __syncthreads();

    if (active) {
        float md = FLT_MAX;
        int c = 0;
        #pragma unroll 8
        for (int k = 0; k < NSLICE; ++k) {
            const float2 pr = part[k * NPOINTS + pidx];
            md = fminf(md, pr.x);
            c += __float_as_int(pr.y);
        }
        float d = sqrtf(fmaxf(md, EPS));
        if (c & 1) d = -d;
        const float val = fmaxf(d + THRESHOLD, 0.0f);
        atomicAdd(&agent_sum[lp / 30], val);   // LDS atomic, 30-way per agent
    }
    __syncthreads();

    if (lp < 10) out[b * 10 + lp] = agent_sum[lp];   // sole writer of batch b
}

extern "C" void kernel_launch(void* const* d_in, const int* in_sizes, int n_in,
                              void* d_out, int out_size, void* d_ws, size_t ws_size,
                              hipStream_t stream) {
    const float* points = (const float*)d_in[0];   // (16,10,30,2)
    const float* polys  = (const float*)d_in[1];   // (16,16,200,2)
    float* out = (float*)d_out;                    // (16,10)

    char* ws = (char*)d_ws;
    float2* part = (float2*)ws;                    // 64*4800*8 B = 2.4 MB
    int*    ctr  = (int*)(ws + (4u << 20));        // 16 ints

    hipMemsetAsync(ctr, 0, NB * sizeof(int), stream);

    dim3 grid(NSLICE, NB);                         // 64 x 16 = 1024 blocks
    seg_kernel<<<grid, 320, 0, stream>>>(points, polys, part, ctr, out);
}

// Round 7
// 79.556 us; speedup vs baseline: 1.4326x; 1.4326x over previous
//
#include <hip/hip_runtime.h>
#include <math.h>
#include <float.h>

#define EPS 1e-6f
#define THRESHOLD 0.5f

#define NB 16
#define NPOLY 16
#define NVERT 200
#define NSEG_PER_POLY 199
#define NSEG (NPOLY * NSEG_PER_POLY)   // 3184 segments per batch
#define NPTB 300                       // points per batch (10 agents * 30)
#define NPOINTS 4800                   // 16 * 300
#define NSLICE 64
#define SEG_PER_SLICE 50               // slices 0..62: 50 segs, slice 63: 34 (both even)

// ---------------------------------------------------------------------------
// Two-kernel structure (R5 skeleton — R6's in-kernel cross-block finalize
// regressed 32 us on threadfence/wbL2 serialization; reverted).
//
// seg_kernel: one block per (batch, slice).
//  Prologue : threads 0..nseg-1 precompute their segment into LDS
//             (both segment-only divides + rcp hoisted).
//  Main loop: lane = point; wave-uniform ds_read_b128 broadcasts; manual 2x
//             unroll with DUAL accumulators (independent fmin/add chains);
//             distance path slimmed (med3 clamp, fma forms — ulp-tolerant);
//             crossing test = rcp fast path + per-lane EXACT-div fallback
//             (bit-matches numpy ref; fallback ~never taken).
//  Epilogue : float2{min_dsq, crossings} partial per (slice, point); slice-0
//             idle lanes (lp 300..309) zero out[] (poisoned 0xAA).
// Exactness: slope_eps = (ey-sy)/((ex-sx)+EPS)+EPS (ref rounding order);
//            cond_y XOR-form exact; inv_esq/fma/med3 feed distance only.
// ---------------------------------------------------------------------------
__global__ __launch_bounds__(320) void seg_kernel(
    const float* __restrict__ points,
    const float* __restrict__ polys,
    float2* __restrict__ part,        // [NSLICE][NPOINTS]
    float* __restrict__ out)
{
    __shared__ float4 lds[SEG_PER_SLICE * 2];

    const int slice = blockIdx.x;       // 0..63
    const int b     = blockIdx.y;       // 0..15
    const int lp    = threadIdx.x;      // 0..319; points 0..299 valid
    const bool active = lp < NPTB;

    const int s0 = slice * SEG_PER_SLICE;
    const int s1 = (s0 + SEG_PER_SLICE < NSEG) ? s0 + SEG_PER_SLICE : NSEG;
    const int nseg = s1 - s0;           // 50 or 34

    // ---- prologue: per-segment precompute into LDS ----
    if (lp < nseg) {
        const int s = s0 + lp;
        const int m = s / NSEG_PER_POLY;
        const int v = s % NSEG_PER_POLY;
        const float2* poly = (const float2*)polys + ((size_t)(b * NPOLY + m) * NVERT);
        const float2 S = poly[v];
        const float2 E = poly[v + 1];
        const float evx = E.x - S.x;
        const float evy = E.y - S.y;
        const float esq = evx * evx + evy * evy;
        const float inv_esq = 1.0f / (esq + EPS);
        const float slope_eps = evy / (evx + EPS) + EPS;  // exact IEEE, ref order
        const float inv_slope = __builtin_amdgcn_rcpf(slope_eps);
        lds[lp * 2]     = make_float4(S.x, S.y, evx, evy);
        lds[lp * 2 + 1] = make_float4(inv_esq, slope_eps, inv_slope, E.y);
    }
    __syncthreads();

    const int pidx = b * NPTB + (active ? lp : 0);
    const float2 pt = *(const float2*)(points + (size_t)pidx * 2);
    const float px = pt.x, py = pt.y;

    float min_a = FLT_MAX, min_b = FLT_MAX;
    int cr_a = 0, cr_b = 0;

    auto body = [&](int j, float& mn, int& cr) {
        const float4 p0 = lds[j * 2];       // wave-uniform -> broadcast
        const float4 p1 = lds[j * 2 + 1];
        const float sx = p0.x, sy = p0.y, evx = p0.z, evy = p0.w;
        const float inv_esq = p1.x, slope_eps = p1.y, inv_slope = p1.z, ey = p1.w;

        // ---- point-to-segment squared distance (ulp-tolerant path) ----
        const float v1x = px - sx;
        const float v1y = py - sy;
        const float dot = fmaf(v1y, evy, v1x * evx);
        const float t   = __builtin_amdgcn_fmed3f(dot * inv_esq, 0.0f, 1.0f);
        const float dx  = fmaf(-evx, t, v1x);
        const float dy  = fmaf(-evy, t, v1y);
        const float dsq = fmaf(dy, dy, dx * dx);
        mn = fminf(mn, dsq);

        // ---- even-odd crossing: rcp fast path + exact-div fallback ----
        const bool cond_y = (sy <= py) != (ey <= py);   // == ref's cond_y, exact
        const float q    = v1y * inv_slope;             // ~3 ulp
        const float ixa  = sx + q;
        const float diff = ixa - px;
        const float err  = fmaf(fabsf(q) + fabsf(ixa), 1e-6f, 1e-30f);
        bool left = diff > 0.0f;
        if (cond_y && !(fabsf(diff) > err)) {
            // rare: decision within rcp noise — replicate ref bit-exactly
            left = (sx + v1y / slope_eps) > px;
        }
        cr += (cond_y && left) ? 1 : 0;
    };

    // nseg is even (50 or 34): clean 2x unroll, independent chains
    for (int j = 0; j < nseg; j += 2) {
        body(j,     min_a, cr_a);
        body(j + 1, min_b, cr_b);
    }

    if (active) {
        part[slice * NPOINTS + pidx] =
            make_float2(fminf(min_a, min_b), __int_as_float(cr_a + cr_b));
    } else if (slice == 0 && lp >= NPTB && lp < NPTB + 10) {
        // zero out[] (poisoned 0xAA); final_kernel atomics run after seg
        // completes (stream order) — race-free.
        out[b * 10 + (lp - NPTB)] = 0.0f;
    }
}

// ---------------------------------------------------------------------------
// Per-point reduction over 64 slices + epilogue + atomic into out.
// ---------------------------------------------------------------------------
__global__ __launch_bounds__(256) void final_kernel(
    const float2* __restrict__ part,
    float* __restrict__ out)
{
    const int p = blockIdx.x * 256 + threadIdx.x;
    if (p >= NPOINTS) return;

    float md = FLT_MAX;
    int c = 0;
    #pragma unroll 8
    for (int k = 0; k < NSLICE; ++k) {
        const float2 pr = part[k * NPOINTS + p];
        md = fminf(md, pr.x);
        c += __float_as_int(pr.y);
    }

    float d = sqrtf(fmaxf(md, EPS));
    if (c & 1) d = -d;
    const float val = fmaxf(d + THRESHOLD, 0.0f);

    const int b = p / NPTB;
    const int a = (p % NPTB) / 30;
    atomicAdd(out + b * 10 + a, val);
}

extern "C" void kernel_launch(void* const* d_in, const int* in_sizes, int n_in,
                              void* d_out, int out_size, void* d_ws, size_t ws_size,
                              hipStream_t stream) {
    const float* points = (const float*)d_in[0];   // (16,10,30,2)
    const float* polys  = (const float*)d_in[1];   // (16,16,200,2)
    float* out = (float*)d_out;                    // (16,10)

    float2* part = (float2*)d_ws;                  // 64*4800*8 B = 2.4 MB

    dim3 grid(NSLICE, NB);                         // 64 x 16 = 1024 blocks
    seg_kernel<<<grid, 320, 0, stream>>>(points, polys, part, out);
    final_kernel<<<(NPOINTS + 255) / 256, 256, 0, stream>>>(part, out);
}